// Round 5
// baseline (150.028 us; speedup 1.0000x reference)
//
#include <hip/hip_runtime.h>

// PointCloudCompletionLoss — fused Chamfer-L2, Gram trick, 16 X/lane.
// d(x,y) = |x|^2 + t, t = |y|^2 - 2 x.y (3 fma; LDS tile holds {-2y,|y|^2}).
// |x|^2 added after min over y => d >= 0 => uint-bit atomicMin order-correct.
// 16 X per lane: per Y-pair per wave = 2 ds_read_b128 + 112 VALU, so the LDS
// pipe (2x12=24 cyc) hides fully under VALU issue (224 cyc) even with 4
// SIMDs sharing LDS. Finalize fused via ticket; ticket counter shares the
// 0x7F memset with mins (start value 0x7F7F7F7F is deterministic).
constexpr int NMINS = 102400;   // 4096 + 3*32768 directed mins
constexpr int NBLK  = 576;      // 2304 waves / 4
constexpr unsigned TICKET_LAST = 0x7F7F7F7Fu + (unsigned)(NBLK - 1);

// Directed passes (X -> min over Y), 1024 X per wave, 256-Y splits:
//  p0: coarse(4096)->gt   tiles  4  splits 32  waves  128  mins[    0..4096)
//  p1: gt(32768)->coarse  tiles 32  splits  4  waves  128  mins[ 4096..36864)
//  p2: fine(32768)->gt    tiles 32  splits 32  waves 1024  mins[36864..69632)
//  p3: gt(32768)->fine    tiles 32  splits 32  waves 1024  mins[69632..102400)

__global__ __launch_bounds__(256) void pccl_stage(
    const float* __restrict__ Xc, const float* __restrict__ Xf,
    const float* __restrict__ G,
    const int* __restrict__ pc, const int* __restrict__ pf,
    unsigned* __restrict__ mins, unsigned* __restrict__ counter,
    float* __restrict__ out)
{
    __shared__ float4 yb[4][256];   // per-wave Y tile: {-2y0,-2y1,-2y2,|y|^2}
    const int wv   = __builtin_amdgcn_readfirstlane(threadIdx.x >> 6);
    const int lane = threadIdx.x & 63;
    const int W    = blockIdx.x * 4 + wv;

    const float* Xp; const float* Yp;
    int NX, NY, txb, local, mbase;
    if (W < 128)        { Xp = Xc; Yp = G;  NX = 1024; NY = 8192; txb = 0; local = W;        mbase = 0; }
    else if (W < 256)   { Xp = G;  Yp = Xc; NX = 8192; NY = 1024; txb = 3; local = W - 128;  mbase = 4096; }
    else if (W < 1280)  { Xp = Xf; Yp = G;  NX = 8192; NY = 8192; txb = 3; local = W - 256;  mbase = 36864; }
    else                { Xp = G;  Yp = Xf; NX = 8192; NY = 8192; txb = 3; local = W - 1280; mbase = 69632; }
    const int xt   = local & ((4 << txb) - 1);       // batch * xtile
    const int sp   = local >> (txb + 2);             // Y-split index
    const int b    = xt >> txb;
    const int xoff = (xt & ((1 << txb) - 1)) << 10;  // * 1024

    // ---- stage 256 Y points as {-2y, |y|^2} (wave-local, no barrier) ----
    const float* ys = Yp + ((size_t)b * NY + (size_t)sp * 256) * 3;
    #pragma unroll
    for (int k = 0; k < 4; ++k) {
        const int i = lane + 64 * k;
        const float y0 = ys[i * 3 + 0], y1 = ys[i * 3 + 1], y2 = ys[i * 3 + 2];
        const float w  = y0 * y0 + y1 * y1 + y2 * y2;
        yb[wv][i] = make_float4(-2.f * y0, -2.f * y1, -2.f * y2, w);
    }

    // ---- X coords in registers: 16 X points per lane ----
    float x0[16], x1[16], x2[16], best[16];
    const float* xs = Xp + ((size_t)b * NX + xoff) * 3;
    #pragma unroll
    for (int k = 0; k < 16; ++k) {
        const int xi = lane + 64 * k;
        x0[k] = xs[xi * 3 + 0];
        x1[k] = xs[xi * 3 + 1];
        x2[k] = xs[xi * 3 + 2];
        best[k] = 3.0e38f;
    }

    // ---- inner: per Y-pair: 2 ds_read_b128 + 16*(6 fma + 1 min3) ----
    #pragma unroll 2
    for (int j = 0; j < 256; j += 2) {
        const float4 ya = yb[wv][j];
        const float4 yc = yb[wv][j + 1];
        #pragma unroll
        for (int k = 0; k < 16; ++k) {
            const float t0 = fmaf(x0[k], ya.x, fmaf(x1[k], ya.y, fmaf(x2[k], ya.z, ya.w)));
            const float t1 = fmaf(x0[k], yc.x, fmaf(x1[k], yc.y, fmaf(x2[k], yc.z, yc.w)));
            best[k] = fminf(fminf(best[k], t0), t1);
        }
    }

    // ---- epilogue: d = |x|^2 + min_t, clamp >= 0, uint-bit atomicMin ----
    unsigned* mp = mins + mbase + b * NX + xoff;
    #pragma unroll
    for (int k = 0; k < 16; ++k) {
        const float x2s = fmaf(x0[k], x0[k], fmaf(x1[k], x1[k], x2[k] * x2[k]));
        const float d = fmaxf(x2s + best[k], 0.0f);
        atomicMin(mp + lane + 64 * k, __float_as_uint(d));
    }

    // ---- ticketed finalize (counter pre-set to 0x7F7F7F7F by the memset) ----
    __threadfence();
    __syncthreads();
    __shared__ unsigned sticket;
    if (threadIdx.x == 0) sticket = atomicAdd(counter, 1u);
    __syncthreads();
    if (sticket != TICKET_LAST) return;
    __threadfence();

    // last block: coherent (device-scope relaxed atomic) loads, full BW
    float s[4] = {0.f, 0.f, 0.f, 0.f};
    #pragma unroll 8
    for (int it = 0; it < NMINS / 256; ++it) {
        const int i = it * 256 + threadIdx.x;
        const unsigned u = __hip_atomic_load(&mins[i], __ATOMIC_RELAXED,
                                             __HIP_MEMORY_SCOPE_AGENT);
        const int seg = (it < 16) ? 0 : (it < 144) ? 1 : (it < 272) ? 2 : 3;
        s[seg] += __uint_as_float(u);
    }
    #pragma unroll
    for (int c = 0; c < 4; ++c) {
        #pragma unroll
        for (int off = 32; off > 0; off >>= 1)
            s[c] += __shfl_down(s[c], off, 64);
    }
    __shared__ float sm[4][4];
    if (lane == 0) {
        sm[wv][0] = s[0]; sm[wv][1] = s[1]; sm[wv][2] = s[2]; sm[wv][3] = s[3];
    }
    __syncthreads();
    if (threadIdx.x == 0) {
        const float S0 = sm[0][0] + sm[1][0] + sm[2][0] + sm[3][0];
        const float S1 = sm[0][1] + sm[1][1] + sm[2][1] + sm[3][1];
        const float S2 = sm[0][2] + sm[1][2] + sm[2][2] + sm[3][2];
        const float S3 = sm[0][3] + sm[1][3] + sm[2][3] + sm[3][3];
        out[0] = (S0 * (1.f / 4096.f) + S1 * (1.f / 32768.f)) * (float)pc[0];
        out[1] = ((S2 + S3) * (1.f / 32768.f)) * (float)pf[0];
    }
}

extern "C" void kernel_launch(void* const* d_in, const int* in_sizes, int n_in,
                              void* d_out, int out_size, void* d_ws, size_t ws_size,
                              hipStream_t stream) {
    const float* coarse = (const float*)d_in[0];
    const float* fine   = (const float*)d_in[1];
    const float* gt     = (const float*)d_in[2];
    const int*   pc     = (const int*)d_in[3];
    const int*   pf     = (const int*)d_in[4];
    float* out = (float*)d_out;

    unsigned* mins    = (unsigned*)d_ws;
    unsigned* counter = mins + NMINS;

    // One memset covers mins (+inf substitute 0x7F7F7F7F for uint-bit min)
    // AND the ticket counter (deterministic start 0x7F7F7F7F).
    hipMemsetAsync(mins, 0x7F, (size_t)NMINS * 4 + 4, stream);
    pccl_stage<<<NBLK, 256, 0, stream>>>(coarse, fine, gt, pc, pf,
                                         mins, counter, out);
}

// Round 6
// 100.390 us; speedup vs baseline: 1.4944x; 1.4944x over previous
//
#include <hip/hip_runtime.h>

// PointCloudCompletionLoss — Chamfer-L2 via split-bf16 MFMA Gram trick.
// t(x,y) = -2 x.y + |y|^2 computed by ONE v_mfma_f32_32x32x16_bf16 per
// 32x32 pair tile. K-slots (11 of 16), with x split as xh+xl, y as yh+yl
// (exact hi/lo split; xl*yl dropped ~2^-17 rel), w=|y|^2 split wh+wl:
//   A(y side, m=lane&31, k=(lane>>5)*8+j):
//     lanes<32:  [yh0,yl0,yh0, yh1,yl1,yh1, yh2,yl2]
//     lanes>=32: [yh2, wh, wl, 0,0,0,0,0]
//   B(x side, n=lane&31, same k mapping), x scaled by -2:
//     lanes<32:  [m2xh0,m2xh0,m2xl0, m2xh1,m2xh1,m2xl1, m2xh2,m2xh2]
//     lanes>=32: [m2xl2, 1, 1, 0,0,0,0,0]
// C/D (measured m74/m101): col=lane&31 = x point; 16 regs x lane-halves
// cover all 32 y rows -> fold regs pairwise into 8 best regs (v_min3),
// final in-lane + xor-32 reduce, d = |x|^2 + tmin >= 0, uint atomicMin.
// Block = 4 waves, owns 512 X x 1024 Y; Y staged packed in 16 KB LDS.
constexpr int NMINS = 102400;   // 4096 + 3*32768 directed mins
constexpr int NBLK  = 1152;

typedef __attribute__((ext_vector_type(8)))  short bf16x8;
typedef __attribute__((ext_vector_type(16))) float f32x16;

// Pass table (block W):
//  p0 [  0, 64): coarse->gt  NX=1024 NY=8192 splits 8  c4/b  2  mbase 0
//  p1 [ 64,128): gt->coarse  NX=8192 NY=1024 splits 1  c4/b 16  mbase 4096
//  p2 [128,640): fine->gt    NX=8192 NY=8192 splits 8  c4/b 16  mbase 36864
//  p3 [640,1152): gt->fine   NX=8192 NY=8192 splits 8  c4/b 16  mbase 69632

__global__ __launch_bounds__(256) void pccl_stage(
    const float* __restrict__ Xc, const float* __restrict__ Xf,
    const float* __restrict__ G, unsigned* __restrict__ mins)
{
    __shared__ uint4 ysh[1024];   // packed Y: [yh0|yl0, yh1|yl1, yh2|yl2, wh|wl]
    const int tid  = threadIdx.x;
    const int lane = tid & 63;
    const int wv   = __builtin_amdgcn_readfirstlane(tid >> 6);
    const int W    = blockIdx.x;

    const float* Xp; const float* Yp;
    int NX, NY, ls, lc, local, mbase;
    if (W < 64)        { Xp=Xc; Yp=G;  NX=1024; NY=8192; ls=3; lc=1; local=W;     mbase=0; }
    else if (W < 128)  { Xp=G;  Yp=Xc; NX=8192; NY=1024; ls=0; lc=4; local=W-64;  mbase=4096; }
    else if (W < 640)  { Xp=Xf; Yp=G;  NX=8192; NY=8192; ls=3; lc=4; local=W-128; mbase=36864; }
    else               { Xp=G;  Yp=Xf; NX=8192; NY=8192; ls=3; lc=4; local=W-640; mbase=69632; }
    const int split  = local & ((1 << ls) - 1);
    const int rest   = local >> ls;
    const int chunk4 = rest & ((1 << lc) - 1);
    const int b      = rest >> lc;

    // ---- cooperative staging of 1024 Y points (4 per thread) ----
    const float* yg = Yp + ((size_t)b * NY + (size_t)split * 1024) * 3;
    #pragma unroll
    for (int it = 0; it < 4; ++it) {
        const int pt = tid + 256 * it;
        const float y0 = yg[pt*3+0], y1 = yg[pt*3+1], y2 = yg[pt*3+2];
        const unsigned uh0 = __float_as_uint(y0) & 0xFFFF0000u;
        const unsigned uh1 = __float_as_uint(y1) & 0xFFFF0000u;
        const unsigned uh2 = __float_as_uint(y2) & 0xFFFF0000u;
        const unsigned sl0 = __float_as_uint(y0 - __uint_as_float(uh0)) >> 16;
        const unsigned sl1 = __float_as_uint(y1 - __uint_as_float(uh1)) >> 16;
        const unsigned sl2 = __float_as_uint(y2 - __uint_as_float(uh2)) >> 16;
        const float w = fmaf(y0, y0, fmaf(y1, y1, y2 * y2));
        const unsigned uhw = __float_as_uint(w) & 0xFFFF0000u;
        const unsigned slw = __float_as_uint(w - __uint_as_float(uhw)) >> 16;
        ysh[pt] = make_uint4((uh0>>16)|(sl0<<16), (uh1>>16)|(sl1<<16),
                             (uh2>>16)|(sl2<<16), (uhw>>16)|(slw<<16));
    }

    // ---- B-frags: 4 frags x 32 X points; lane owns point frag*32+(lane&31) ----
    const int l31 = lane & 31;
    const bool hi = (lane >> 5) != 0;    // k-half of this lane
    const float* xg = Xp + ((size_t)b * NX + (size_t)chunk4 * 512 + (size_t)wv * 128) * 3;
    bf16x8 Bf[4];
    float x2s[4];
    #pragma unroll
    for (int f = 0; f < 4; ++f) {
        const int p = f * 32 + l31;
        const float x0 = xg[p*3+0], x1 = xg[p*3+1], x2 = xg[p*3+2];
        x2s[f] = fmaf(x0, x0, fmaf(x1, x1, x2 * x2));
        const float m0 = -2.f * x0, m1 = -2.f * x1, m2 = -2.f * x2;
        const unsigned uh0 = __float_as_uint(m0) & 0xFFFF0000u;
        const unsigned uh1 = __float_as_uint(m1) & 0xFFFF0000u;
        const unsigned uh2 = __float_as_uint(m2) & 0xFFFF0000u;
        const unsigned sh0 = uh0 >> 16, sh1 = uh1 >> 16, sh2 = uh2 >> 16;
        const unsigned sl0 = __float_as_uint(m0 - __uint_as_float(uh0)) >> 16;
        const unsigned sl1 = __float_as_uint(m1 - __uint_as_float(uh1)) >> 16;
        const unsigned sl2 = __float_as_uint(m2 - __uint_as_float(uh2)) >> 16;
        union { unsigned u[4]; bf16x8 v; } bu;
        bu.u[0] = hi ? (sl2 | (0x3F80u << 16)) : (sh0 | (sh0 << 16));
        bu.u[1] = hi ? 0x3F80u                 : (sl0 | (sh1 << 16));
        bu.u[2] = hi ? 0u                      : (sh1 | (sl1 << 16));
        bu.u[3] = hi ? 0u                      : (sh2 | (sh2 << 16));
        Bf[f] = bu.v;
    }

    __syncthreads();

    float best[4][8];
    #pragma unroll
    for (int f = 0; f < 4; ++f)
        #pragma unroll
        for (int j = 0; j < 8; ++j) best[f][j] = 3.0e38f;

    const f32x16 zc = (f32x16)0.0f;

    #pragma unroll 2
    for (int t = 0; t < 32; ++t) {
        const uint4 dd = ysh[t * 32 + l31];
        union { unsigned u[4]; bf16x8 v; } au;
        au.u[0] = hi ? ((dd.z & 0xFFFFu) | (dd.w << 16))   // [yh2, wh]
                     : dd.x;                               // [yh0, yl0]
        au.u[1] = hi ? (dd.w >> 16)                        // [wl, 0]
                     : ((dd.x & 0xFFFFu) | (dd.y << 16));  // [yh0, yh1]
        au.u[2] = hi ? 0u : ((dd.y >> 16) | (dd.y << 16)); // [yl1, yh1]
        au.u[3] = hi ? 0u : dd.z;                          // [yh2, yl2]
        const bf16x8 Af = au.v;
        #pragma unroll
        for (int f = 0; f < 4; ++f) {
            const f32x16 acc = __builtin_amdgcn_mfma_f32_32x32x16_bf16(Af, Bf[f], zc, 0, 0, 0);
            #pragma unroll
            for (int j = 0; j < 8; ++j)
                best[f][j] = fminf(fminf(best[f][j], acc[2*j]), acc[2*j+1]);
        }
    }

    // ---- epilogue: reduce 8 best + xor-32 half merge; d = |x|^2 + tmin ----
    unsigned* mp = mins + mbase + b * NX + chunk4 * 512 + wv * 128;
    #pragma unroll
    for (int f = 0; f < 4; ++f) {
        const float m0 = fminf(fminf(best[f][0], best[f][1]), best[f][2]);
        const float m1 = fminf(fminf(best[f][3], best[f][4]), best[f][5]);
        const float m2 = fminf(fminf(best[f][6], best[f][7]), m0);
        float tm = fminf(m1, m2);
        tm = fminf(tm, __shfl_xor(tm, 32, 64));
        const float d = fmaxf(x2s[f] + tm, 0.0f);
        atomicMin(mp + f * 32 + l31, __float_as_uint(d));
    }
}

// 100 blocks x 256 threads, uint4/thread (proven in round 4).
__global__ __launch_bounds__(256) void pccl_sum(
    const unsigned* __restrict__ mins,
    const int* __restrict__ pc, const int* __restrict__ pf,
    float* __restrict__ out)
{
    const int tid = blockIdx.x * 256 + threadIdx.x;
    const uint4 v = ((const uint4*)mins)[tid];
    float s = __uint_as_float(v.x) + __uint_as_float(v.y)
            + __uint_as_float(v.z) + __uint_as_float(v.w);
    #pragma unroll
    for (int off = 32; off > 0; off >>= 1) s += __shfl_down(s, off, 64);
    if ((threadIdx.x & 63) == 0) {
        const int i = tid * 4;
        float scale, param; int o;
        if (i < 4096)       { scale = 1.f / 4096.f;  param = (float)pc[0]; o = 0; }
        else if (i < 36864) { scale = 1.f / 32768.f; param = (float)pc[0]; o = 0; }
        else                { scale = 1.f / 32768.f; param = (float)pf[0]; o = 1; }
        atomicAdd(out + o, s * scale * param);
    }
}

extern "C" void kernel_launch(void* const* d_in, const int* in_sizes, int n_in,
                              void* d_out, int out_size, void* d_ws, size_t ws_size,
                              hipStream_t stream) {
    const float* coarse = (const float*)d_in[0];
    const float* fine   = (const float*)d_in[1];
    const float* gt     = (const float*)d_in[2];
    const int*   pc     = (const int*)d_in[3];
    const int*   pf     = (const int*)d_in[4];
    float* out = (float*)d_out;
    unsigned* mins = (unsigned*)d_ws;

    hipMemsetAsync(mins, 0x7F, (size_t)NMINS * 4, stream);  // 3.396e38 sentinel
    hipMemsetAsync(out, 0, 2 * sizeof(float), stream);
    pccl_stage<<<NBLK, 256, 0, stream>>>(coarse, fine, gt, mins);
    pccl_sum<<<NMINS / 1024, 256, 0, stream>>>(mins, pc, pf, out);
}